// Round 7
// baseline (392.132 us; speedup 1.0000x reference)
//
#include <hip/hip_runtime.h>
#include <hip/hip_bf16.h>
#include <math.h>

// B=8, H=W=128, C=hidden=256, N=16384, Mtot=131072.
#define Hc   128
#define Wc   128
#define Cc   256
#define Nc   (Hc * Wc)
#define Bn   8
#define Mtot (Bn * Nc)          // 131072
#define CSZ  52                 // ceil(256/5)
#define SPAD 2

typedef unsigned short ushort4v __attribute__((ext_vector_type(4)));
typedef unsigned short ushort8  __attribute__((ext_vector_type(8)));
typedef __bf16         bf16x8   __attribute__((ext_vector_type(8)));
typedef float          f32x4    __attribute__((ext_vector_type(4)));

__device__ __forceinline__ float bf2f(unsigned short u) {
    return __uint_as_float(((unsigned)u) << 16);
}
__device__ __forceinline__ unsigned short f2bf(float f) {   // RNE
    unsigned u = __float_as_uint(f);
    return (unsigned short)((u + 0x7fffu + ((u >> 16) & 1u)) >> 16);
}
// pack two floats -> two bf16 (a -> low16). Round-half-up (ok vs bf16 eps).
__device__ __forceinline__ unsigned pk2bf(float a, float b) {
    unsigned ua = __float_as_uint(a) + 0x8000u;
    unsigned ub = __float_as_uint(b) + 0x8000u;
    return __builtin_amdgcn_perm(ub, ua, 0x07060302);
}
__device__ __forceinline__ void async16(const void* g, void* l) {
    __builtin_amdgcn_global_load_lds(
        (const __attribute__((address_space(1))) unsigned*)g,
        (__attribute__((address_space(3))) unsigned*)l, 16, 0, 0);
}

// ---------------------------------------------------------------------------
// P0: w1, w2 fp32 -> bf16; dw_w [ch][tap] -> dwT [tap][ch] fp32.
// ---------------------------------------------------------------------------
__global__ __launch_bounds__(256)
void wprep_kernel(const float* __restrict__ w1, const float* __restrict__ w2,
                  const float* __restrict__ dw_w,
                  unsigned short* __restrict__ w1b, unsigned short* __restrict__ w2b,
                  float* __restrict__ dwT)
{
    const int g = blockIdx.x * 256 + threadIdx.x;   // 16384 threads
    {
        float4 a = *(const float4*)(w1 + (size_t)g * 4);
        ushort4v o = { f2bf(a.x), f2bf(a.y), f2bf(a.z), f2bf(a.w) };
        *(ushort4v*)(w1b + (size_t)g * 4) = o;
    }
    {
        float4 a = *(const float4*)(w2 + (size_t)g * 4);
        ushort4v o = { f2bf(a.x), f2bf(a.y), f2bf(a.z), f2bf(a.w) };
        *(ushort4v*)(w2b + (size_t)g * 4) = o;
    }
    if (g < 9 * Cc) dwT[(g % 9) * Cc + g / 9] = dw_w[g];
}

// ---------------------------------------------------------------------------
// P1: H-shift + fp32->bf16 convert (gather form), 8 ch/thread.
// ---------------------------------------------------------------------------
__global__ __launch_bounds__(256)
void shiftcvt_kernel(const float* __restrict__ x, unsigned short* __restrict__ xb)
{
    const int gid0 = blockIdx.x * 256 + threadIdx.x;
#pragma unroll
    for (int it = 0; it < 4; ++it) {
        const int gid = gid0 + it * (4096 * 256);   // 4.19M chunks total
        const int row = gid >> 5;                   // b*16384 + h*128 + w
        const int c   = (gid & 31) * 8;
        const int hh  = (row >> 7) & 127;
        const int s0  = c / CSZ - SPAD;
        const int s1  = (c + 4) / CSZ - SPAD;
        const int h0  = hh - s0, h1r = hh - s1;
        float4 v0 = make_float4(0.f, 0.f, 0.f, 0.f);
        float4 v1 = make_float4(0.f, 0.f, 0.f, 0.f);
        if (h0  >= 0 && h0  < Hc)
            v0 = *(const float4*)(x + ((size_t)row + (size_t)(h0 - hh) * Wc) * Cc + c);
        if (h1r >= 0 && h1r < Hc)
            v1 = *(const float4*)(x + ((size_t)row + (size_t)(h1r - hh) * Wc) * Cc + c + 4);
        uint4 o;
        o.x = pk2bf(v0.x, v0.y); o.y = pk2bf(v0.z, v0.w);
        o.z = pk2bf(v1.x, v1.y); o.w = pk2bf(v1.z, v1.w);
        *(uint4*)(xb + (size_t)row * Cc + c) = o;
    }
}

// ---------------------------------------------------------------------------
// K1: h1 = x_shifted_bf16 @ w1^T + b1. Both panels async16, single-barrier
// 1-step-lookahead, LDS 34816 (Cs unions) -> 4 blocks/CU. (Unchanged.)
// ---------------------------------------------------------------------------
__global__ __launch_bounds__(256)
void fc1_mfma_kernel(const unsigned short* __restrict__ xb, const unsigned short* __restrict__ w1b,
                     const float* __restrict__ b1, unsigned short* __restrict__ h1)
{
    __shared__ __align__(16) unsigned char smem[34816];
    __bf16* As = (__bf16*)smem;                     // [2][128][32]
    __bf16* Bs = (__bf16*)(smem + 16384);           // [2][128][32]
    unsigned short* Cs = (unsigned short*)smem;     // [128][136] epilogue

    const int tid  = threadIdx.x;
    const int lane = tid & 63;
    const int wave = tid >> 6;
    const int wm = (wave >> 1) * 64, wn = (wave & 1) * 64;

    const int lid = ((blockIdx.x & 7) << 8) | (blockIdx.x >> 3);
    const int bx  = lid >> 1;                  // b*128 + h
    const int j0  = (lid & 1) * 128;
    const size_t m0 = (size_t)bx * 128;
    const int idx0 = tid, idx1 = tid + 256;

    const size_t aro0 = (m0 + (idx0 >> 2)) * Cc + (idx0 & 3) * 8;
    const size_t aro1 = (m0 + (idx1 >> 2)) * Cc + (idx1 & 3) * 8;
    const size_t bro0 = (size_t)(j0 + (idx0 >> 2)) * Cc + (idx0 & 3) * 8;
    const size_t bro1 = (size_t)(j0 + (idx1 >> 2)) * Cc + (idx1 & 3) * 8;

    auto stage = [&](int buf, int t) {
        const int k0 = t * 32;
        __bf16* adst = As + buf * 4096;
        __bf16* bdst = Bs + buf * 4096;
        async16(xb  + aro0 + k0, adst + idx0 * 8);
        async16(xb  + aro1 + k0, adst + idx1 * 8);
        async16(w1b + bro0 + k0, bdst + idx0 * 8);
        async16(w1b + bro1 + k0, bdst + idx1 * 8);
    };

    f32x4 acc[4][4] = {};
    const int kq = (lane >> 4) * 8;
    const int rr = lane & 15;

    stage(0, 0);
    __syncthreads();

    int cur = 0;
    for (int t = 0; t < 8; ++t) {
        const int nxt = cur ^ 1;
        if (t < 7) stage(nxt, t + 1);
        bf16x8 a[4], b[4];
        const __bf16* ap = As + cur * 4096;
        const __bf16* bp = Bs + cur * 4096;
#pragma unroll
        for (int i = 0; i < 4; ++i) {
            a[i] = *(const bf16x8*)(ap + (wm + i * 16 + rr) * 32 + kq);
            b[i] = *(const bf16x8*)(bp + (wn + i * 16 + rr) * 32 + kq);
        }
#pragma unroll
        for (int i = 0; i < 4; ++i)
#pragma unroll
            for (int j = 0; j < 4; ++j)
                acc[i][j] = __builtin_amdgcn_mfma_f32_16x16x32_bf16(a[i], b[j], acc[i][j], 0, 0, 0);
        __syncthreads();
        cur = nxt;
    }

    const int cq = (lane >> 4) * 4;
    const int cc = lane & 15;
    float bv[4];
#pragma unroll
    for (int j = 0; j < 4; ++j) bv[j] = b1[j0 + wn + j * 16 + cc];
#pragma unroll
    for (int i = 0; i < 4; ++i)
#pragma unroll
        for (int j = 0; j < 4; ++j) {
            const int col = wn + j * 16 + cc;
#pragma unroll
            for (int rg = 0; rg < 4; ++rg)
                Cs[(wm + i * 16 + cq + rg) * 136 + col] = f2bf(acc[i][j][rg] + bv[j]);
        }
    __syncthreads();
    {
        const int row = tid >> 1, hf = tid & 1;
        const unsigned short* src = Cs + row * 136 + hf * 64;
        unsigned short* dst = h1 + (m0 + row) * Cc + j0 + hf * 64;
#pragma unroll
        for (int i = 0; i < 8; ++i)
            *(uint4*)(dst + i * 8) = *(const uint4*)(src + i * 8);
    }
}

// ---------------------------------------------------------------------------
// K2 v2: FUSED dwconv3x3+bias+GELU+W-shift+fc2, k-slab pipelined.
// One block per (row, j-half): grid 2048, N split across 2 blocks (acc stays
// 64 VGPR; dwconv done twice per row — cheap VALU vs occupancy win).
// Per k-slab t (32 channels, self-contained under the per-channel W-shift):
//   GATHER form A[wa][c] = valid(wa-s_c) ? gelu(conv(b,hh,wa-s_c,c)) : 0
//   (no LDS pre-zero, no scatter -> kills r6's 32-way zeroing conflicts).
// Pipeline: {stageB(t+1) async16 + h1 loads(t+1)} -> MFMA(t) -> {conv FMAs +
// gelu + ds_write A(t+1)} -> barrier. A/B double-buffered: LDS 32768 B
// (was 81920 -> 2 blocks/CU; now 3-4 blocks/CU, phases overlap).
// A-slab XOR-swizzled at 16B granularity; read XOR folds into frag addr.
// ---------------------------------------------------------------------------
__global__ __launch_bounds__(256)
void dwfc2_kernel(const unsigned short* __restrict__ h1,
                  const float* __restrict__ dwT, const float* __restrict__ dw_b,
                  const unsigned short* __restrict__ w2b, const float* __restrict__ b2,
                  float* __restrict__ out)
{
    __shared__ __align__(16) unsigned char smem[32768];
    __bf16* Ash = (__bf16*)smem;               // [2][128 w][32 ch] xor16
    __bf16* Bs  = (__bf16*)(smem + 16384);     // [2][128 j][32 k] linear

    const int tid  = threadIdx.x;
    const int lane = tid & 63;
    const int wave = tid >> 6;
    const int wm = (wave >> 1) * 64, wn = (wave & 1) * 64;

    // grid 2048 (div 8): bijective XCD swizzle; j-half pair adjacent -> shared
    // h1 rows hit the same XCD L2.
    const int lid = ((blockIdx.x & 7) << 8) | (blockIdx.x >> 3);
    const int bx  = lid >> 1;              // b*128 + h
    const int j0  = (lid & 1) * 128;
    const int bb  = bx >> 7, hh = bx & 127;
    const size_t m0 = (size_t)bx * 128;

    // dwconv mapping: tc = ch-quad (4 ch), tw = w-quad (4 wa). Lanes sweep tc
    // fastest -> h1 loads coalesce (8 lanes x 8B contiguous per (dy,w)).
    const int tc = tid & 7, tw = tid >> 3;

    // B staging (as fc1)
    const int idx0 = tid, idx1 = tid + 256;
    const size_t bro0 = (size_t)(j0 + (idx0 >> 2)) * Cc + (idx0 & 3) * 8;
    const size_t bro1 = (size_t)(j0 + (idx1 >> 2)) * Cc + (idx1 & 3) * 8;
    auto stageB = [&](int buf, int t) {
        const int k0 = t * 32;
        __bf16* bdst = Bs + buf * 4096;
        async16(w2b + bro0 + k0, bdst + idx0 * 8);
        async16(w2b + bro1 + k0, bdst + idx1 * 8);
    };

    // h1 gather loads for slab t: source rows y=hh-1..hh+1, source w =
    // wp-1..wp+4 where wp = tw*4 - s (s uniform over the 4-ch quad: 4 | 52).
    uint2 inr[3][6];
    auto loadsDW = [&](int t) {
        const int c0g = t * 32 + tc * 4;
        const int s   = c0g / CSZ - SPAD;
        const int wp  = tw * 4 - s;
#pragma unroll
        for (int dy = 0; dy < 3; ++dy) {
            const int y = hh + dy - 1;
            const bool oky = (unsigned)y < (unsigned)Hc;
            const unsigned short* rp = h1 + ((size_t)bb * Nc + (size_t)y * Wc) * Cc + c0g;
#pragma unroll
            for (int dx = 0; dx < 6; ++dx) {
                const int wi = wp - 1 + dx;
                uint2 v; v.x = 0u; v.y = 0u;
                if (oky && (unsigned)wi < (unsigned)Wc)
                    v = *(const uint2*)(rp + (size_t)wi * Cc);
                inr[dy][dx] = v;
            }
        }
    };
    // conv FMAs + gelu + validity-zero + ds_write into Ash[buf] (xor16 swz).
    auto mathDW = [&](int t, int buf) {
        const int c0g = t * 32 + tc * 4;
        const int s   = c0g / CSZ - SPAD;
        const int wp  = tw * 4 - s;
        float4 bv = *(const float4*)(dw_b + c0g);
        float acc4[4][4];
#pragma unroll
        for (int i = 0; i < 4; ++i) {
            acc4[i][0] = bv.x; acc4[i][1] = bv.y; acc4[i][2] = bv.z; acc4[i][3] = bv.w;
        }
#pragma unroll
        for (int dy = 0; dy < 3; ++dy) {
            float fin[6][4];
#pragma unroll
            for (int dx = 0; dx < 6; ++dx) {
                const uint2 r = inr[dy][dx];
                fin[dx][0] = bf2f((unsigned short)(r.x & 0xffffu));
                fin[dx][1] = bf2f((unsigned short)(r.x >> 16));
                fin[dx][2] = bf2f((unsigned short)(r.y & 0xffffu));
                fin[dx][3] = bf2f((unsigned short)(r.y >> 16));
            }
#pragma unroll
            for (int tx = 0; tx < 3; ++tx) {
                const float4 wv = *(const float4*)(dwT + (dy * 3 + tx) * Cc + c0g);
#pragma unroll
                for (int i = 0; i < 4; ++i) {
                    acc4[i][0] = __builtin_fmaf(fin[i + tx][0], wv.x, acc4[i][0]);
                    acc4[i][1] = __builtin_fmaf(fin[i + tx][1], wv.y, acc4[i][1]);
                    acc4[i][2] = __builtin_fmaf(fin[i + tx][2], wv.z, acc4[i][2]);
                    acc4[i][3] = __builtin_fmaf(fin[i + tx][3], wv.w, acc4[i][3]);
                }
            }
        }
#pragma unroll
        for (int i = 0; i < 4; ++i) {
            const bool valid = (unsigned)(wp + i) < (unsigned)Wc;
            float g[4];
#pragma unroll
            for (int c = 0; c < 4; ++c) {
                const float v = acc4[i][c];
                const float u = v * v;
                const float a = __builtin_fmaf(0.0713548162f, u, 1.5957691216f);
                const float e = __expf(v * a);
                g[c] = valid ? (v * e * __builtin_amdgcn_rcpf(e + 1.0f)) : 0.f;
            }
            uint2 o; o.x = pk2bf(g[0], g[1]); o.y = pk2bf(g[2], g[3]);
            const int row  = tw * 4 + i;
            const int eoff = (tc * 4) ^ (((row >> 2) & 3) << 3);   // 16B-gran XOR
            *(uint2*)(Ash + buf * 4096 + row * 32 + eoff) = o;
        }
    };

    f32x4 acc[4][4] = {};
    const int kq = (lane >> 4) * 8;
    const int rr = lane & 15;

    // prologue: slab 0
    loadsDW(0);
    stageB(0, 0);
    mathDW(0, 0);
    __syncthreads();

    int cur = 0;
    for (int t = 0; t < 8; ++t) {
        const int nxt = cur ^ 1;
        if (t < 7) {
            stageB(nxt, t + 1);
            loadsDW(t + 1);            // global latency hides under MFMA(t)
        }
        bf16x8 a[4], b[4];
        const __bf16* ap = Ash + cur * 4096;
        const __bf16* bp = Bs  + cur * 4096;
#pragma unroll
        for (int i = 0; i < 4; ++i) {
            const int rowA = wm + i * 16 + rr;
            a[i] = *(const bf16x8*)(ap + rowA * 32 + (kq ^ (((rowA >> 2) & 3) << 3)));
            b[i] = *(const bf16x8*)(bp + (wn + i * 16 + rr) * 32 + kq);
        }
#pragma unroll
        for (int i = 0; i < 4; ++i)
#pragma unroll
            for (int j = 0; j < 4; ++j)
                acc[i][j] = __builtin_amdgcn_mfma_f32_16x16x32_bf16(a[i], b[j], acc[i][j], 0, 0, 0);
        if (t < 7) mathDW(t + 1, nxt); // VALU overlaps other blocks' MFMA
        __syncthreads();
        cur = nxt;
    }

    const int cq = (lane >> 4) * 4;
    const int cc = lane & 15;
    float bv[4];
#pragma unroll
    for (int j = 0; j < 4; ++j) bv[j] = b2[j0 + wn + j * 16 + cc];
#pragma unroll
    for (int i = 0; i < 4; ++i)
#pragma unroll
        for (int j = 0; j < 4; ++j) {
            const int col = j0 + wn + j * 16 + cc;
#pragma unroll
            for (int rg = 0; rg < 4; ++rg)
                out[(m0 + wm + i * 16 + cq + rg) * Cc + col] = acc[i][j][rg] + bv[j];
        }
}

extern "C" void kernel_launch(void* const* d_in, const int* in_sizes, int n_in,
                              void* d_out, int out_size, void* d_ws, size_t ws_size,
                              hipStream_t stream) {
    // inputs: x, H, W, w1, b1, dw_w, dw_b, w2, b2
    const float* x    = (const float*)d_in[0];
    const float* w1   = (const float*)d_in[3];
    const float* b1   = (const float*)d_in[4];
    const float* dw_w = (const float*)d_in[5];
    const float* dw_b = (const float*)d_in[6];
    const float* w2   = (const float*)d_in[7];
    const float* b2   = (const float*)d_in[8];
    float* out = (float*)d_out;

    // ws layout:
    //   [0,64MB)    h1 bf16
    //   [64,128MB)  xb bf16 (shifted x; only fc1 reads it)
    //   [128MB..)   w1b bf16 (128 KB), w2b bf16 (128 KB), dwT fp32 (9 KB)
    unsigned short* h1  = (unsigned short*)d_ws;
    unsigned short* xb  = h1 + (size_t)Mtot * Cc;
    unsigned short* w1b = xb + (size_t)Mtot * Cc;
    unsigned short* w2b = w1b + 65536;
    float*          dwT = (float*)(w2b + 65536);

    wprep_kernel<<<dim3(64), dim3(256), 0, stream>>>(w1, w2, dw_w, w1b, w2b, dwT);
    shiftcvt_kernel<<<dim3(4096), dim3(256), 0, stream>>>(x, xb);
    fc1_mfma_kernel<<<dim3(2 * Mtot / 128), dim3(256), 0, stream>>>(xb, w1b, b1, h1);
    dwfc2_kernel<<<dim3(2 * Mtot / 128), dim3(256), 0, stream>>>(h1, dwT, dw_b, w2b, b2, out);
}

// Round 8
// 353.096 us; speedup vs baseline: 1.1106x; 1.1106x over previous
//
#include <hip/hip_runtime.h>
#include <hip/hip_bf16.h>
#include <math.h>

// B=8, H=W=128, C=hidden=256, N=16384, Mtot=131072.
#define Hc   128
#define Wc   128
#define Cc   256
#define Nc   (Hc * Wc)
#define Bn   8
#define Mtot (Bn * Nc)          // 131072
#define CSZ  52                 // ceil(256/5)
#define SPAD 2

typedef unsigned short ushort4v __attribute__((ext_vector_type(4)));
typedef unsigned short ushort8  __attribute__((ext_vector_type(8)));
typedef __bf16         bf16x8   __attribute__((ext_vector_type(8)));
typedef float          f32x4    __attribute__((ext_vector_type(4)));

__device__ __forceinline__ float bf2f(unsigned short u) {
    return __uint_as_float(((unsigned)u) << 16);
}
__device__ __forceinline__ unsigned short f2bf(float f) {   // RNE
    unsigned u = __float_as_uint(f);
    return (unsigned short)((u + 0x7fffu + ((u >> 16) & 1u)) >> 16);
}
// pack two floats -> two bf16 (a -> low16). Round-half-up (ok vs bf16 eps).
__device__ __forceinline__ unsigned pk2bf(float a, float b) {
    unsigned ua = __float_as_uint(a) + 0x8000u;
    unsigned ub = __float_as_uint(b) + 0x8000u;
    return __builtin_amdgcn_perm(ub, ua, 0x07060302);
}
__device__ __forceinline__ void async16(const void* g, void* l) {
    __builtin_amdgcn_global_load_lds(
        (const __attribute__((address_space(1))) unsigned*)g,
        (__attribute__((address_space(3))) unsigned*)l, 16, 0, 0);
}

// ---------------------------------------------------------------------------
// P0+P1 merged: H-shift + fp32->bf16 convert of x (all 4096 blocks), plus
// weight prep (blocks 0..63): w1,w2 fp32->bf16; dw_w [ch][tap]->dwT [tap][ch].
// Shift gather form: xb[(b,h,w)][c] = (0 <= h-s_c < H) ? bf16(x[..h-s_c..][c])
// : 0, s_c = c/52 - 2. 8 ch/thread; a 4-chunk never crosses a 52-boundary.
// ---------------------------------------------------------------------------
__global__ __launch_bounds__(256)
void shiftwprep_kernel(const float* __restrict__ x, unsigned short* __restrict__ xb,
                       const float* __restrict__ w1, const float* __restrict__ w2,
                       const float* __restrict__ dw_w,
                       unsigned short* __restrict__ w1b, unsigned short* __restrict__ w2b,
                       float* __restrict__ dwT)
{
    const int gid0 = blockIdx.x * 256 + threadIdx.x;
    if (blockIdx.x < 64) {                            // weight prep (16384 thr)
        const int g = gid0;
        {
            float4 a = *(const float4*)(w1 + (size_t)g * 4);
            ushort4v o = { f2bf(a.x), f2bf(a.y), f2bf(a.z), f2bf(a.w) };
            *(ushort4v*)(w1b + (size_t)g * 4) = o;
        }
        {
            float4 a = *(const float4*)(w2 + (size_t)g * 4);
            ushort4v o = { f2bf(a.x), f2bf(a.y), f2bf(a.z), f2bf(a.w) };
            *(ushort4v*)(w2b + (size_t)g * 4) = o;
        }
        if (g < 9 * Cc) dwT[(g % 9) * Cc + g / 9] = dw_w[g];
    }
#pragma unroll
    for (int it = 0; it < 4; ++it) {
        const int gid = gid0 + it * (4096 * 256);   // 4.19M chunks total
        const int row = gid >> 5;                   // b*16384 + h*128 + w
        const int c   = (gid & 31) * 8;
        const int hh  = (row >> 7) & 127;
        const int s0  = c / CSZ - SPAD;
        const int s1  = (c + 4) / CSZ - SPAD;
        const int h0  = hh - s0, h1r = hh - s1;
        float4 v0 = make_float4(0.f, 0.f, 0.f, 0.f);
        float4 v1 = make_float4(0.f, 0.f, 0.f, 0.f);
        if (h0  >= 0 && h0  < Hc)
            v0 = *(const float4*)(x + ((size_t)row + (size_t)(h0 - hh) * Wc) * Cc + c);
        if (h1r >= 0 && h1r < Hc)
            v1 = *(const float4*)(x + ((size_t)row + (size_t)(h1r - hh) * Wc) * Cc + c + 4);
        uint4 o;
        o.x = pk2bf(v0.x, v0.y); o.y = pk2bf(v0.z, v0.w);
        o.z = pk2bf(v1.x, v1.y); o.w = pk2bf(v1.z, v1.w);
        *(uint4*)(xb + (size_t)row * Cc + c) = o;
    }
}

// ---------------------------------------------------------------------------
// K1: h1 = x_shifted_bf16 @ w1^T + b1. Both panels async16, single-barrier
// 1-step-lookahead, LDS 34816 (Cs unions) -> 4 blocks/CU. (r5-proven.)
// ---------------------------------------------------------------------------
__global__ __launch_bounds__(256)
void fc1_mfma_kernel(const unsigned short* __restrict__ xb, const unsigned short* __restrict__ w1b,
                     const float* __restrict__ b1, unsigned short* __restrict__ h1)
{
    __shared__ __align__(16) unsigned char smem[34816];
    __bf16* As = (__bf16*)smem;                     // [2][128][32]
    __bf16* Bs = (__bf16*)(smem + 16384);           // [2][128][32]
    unsigned short* Cs = (unsigned short*)smem;     // [128][136] epilogue

    const int tid  = threadIdx.x;
    const int lane = tid & 63;
    const int wave = tid >> 6;
    const int wm = (wave >> 1) * 64, wn = (wave & 1) * 64;

    // nwg = 2048 (div by 8): bijective XCD swizzle.
    const int lid = ((blockIdx.x & 7) << 8) | (blockIdx.x >> 3);
    const int bx  = lid >> 1;                  // b*128 + h
    const int j0  = (lid & 1) * 128;
    const size_t m0 = (size_t)bx * 128;
    const int idx0 = tid, idx1 = tid + 256;    // 16B chunks per panel

    const size_t aro0 = (m0 + (idx0 >> 2)) * Cc + (idx0 & 3) * 8;
    const size_t aro1 = (m0 + (idx1 >> 2)) * Cc + (idx1 & 3) * 8;
    const size_t bro0 = (size_t)(j0 + (idx0 >> 2)) * Cc + (idx0 & 3) * 8;
    const size_t bro1 = (size_t)(j0 + (idx1 >> 2)) * Cc + (idx1 & 3) * 8;

    auto stage = [&](int buf, int t) {
        const int k0 = t * 32;
        __bf16* adst = As + buf * 4096;
        __bf16* bdst = Bs + buf * 4096;
        async16(xb  + aro0 + k0, adst + idx0 * 8);
        async16(xb  + aro1 + k0, adst + idx1 * 8);
        async16(w1b + bro0 + k0, bdst + idx0 * 8);
        async16(w1b + bro1 + k0, bdst + idx1 * 8);
    };

    f32x4 acc[4][4] = {};
    const int kq = (lane >> 4) * 8;
    const int rr = lane & 15;

    stage(0, 0);
    __syncthreads();

    int cur = 0;
    for (int t = 0; t < 8; ++t) {
        const int nxt = cur ^ 1;
        if (t < 7) stage(nxt, t + 1);   // issue next tile BEFORE compute
        bf16x8 a[4], b[4];
        const __bf16* ap = As + cur * 4096;
        const __bf16* bp = Bs + cur * 4096;
#pragma unroll
        for (int i = 0; i < 4; ++i) {
            a[i] = *(const bf16x8*)(ap + (wm + i * 16 + rr) * 32 + kq);
            b[i] = *(const bf16x8*)(bp + (wn + i * 16 + rr) * 32 + kq);
        }
#pragma unroll
        for (int i = 0; i < 4; ++i)
#pragma unroll
            for (int j = 0; j < 4; ++j)
                acc[i][j] = __builtin_amdgcn_mfma_f32_16x16x32_bf16(a[i], b[j], acc[i][j], 0, 0, 0);
        __syncthreads();                // drains next-tile loads (m97 structure)
        cur = nxt;
    }

    const int cq = (lane >> 4) * 4;
    const int cc = lane & 15;
    float bv[4];
#pragma unroll
    for (int j = 0; j < 4; ++j) bv[j] = b1[j0 + wn + j * 16 + cc];
#pragma unroll
    for (int i = 0; i < 4; ++i)
#pragma unroll
        for (int j = 0; j < 4; ++j) {
            const int col = wn + j * 16 + cc;
#pragma unroll
            for (int rg = 0; rg < 4; ++rg)
                Cs[(wm + i * 16 + cq + rg) * 136 + col] = f2bf(acc[i][j][rg] + bv[j]);
        }
    __syncthreads();
    {
        const int row = tid >> 1, hf = tid & 1;
        const unsigned short* src = Cs + row * 136 + hf * 64;
        unsigned short* dst = h1 + (m0 + row) * Cc + j0 + hf * 64;
#pragma unroll
        for (int i = 0; i < 8; ++i)
            *(uint4*)(dst + i * 8) = *(const uint4*)(src + i * 8);
    }
}

// ---------------------------------------------------------------------------
// K2: depthwise 3x3 + bias + GELU + W-shift scatter, ONE BLOCK PER (b,h) ROW
// (grid 1024). The W-shift permutes only within a row, so this block owns
// every write to its row of gsh: zero the 4 border columns, barrier, then the
// r5-proven quarter-row scatter body looped qtr=0..3. Replaces the separate
// zero_borders dispatch (no cross-block race: single-writer-block per row).
// 256 threads = 32 channel-groups (t&31) x 8 w-quads (t>>5); r5 VGPR profile
// preserved (no weight hoisting — that caused r6/r7's VGPR/occupancy loss).
// ---------------------------------------------------------------------------
__global__ __launch_bounds__(256)
void dwconv_gelu_scatter_kernel(const unsigned short* __restrict__ h1,
                                const float* __restrict__ dwT, const float* __restrict__ dw_b,
                                unsigned short* __restrict__ gsh)
{
    const int t   = threadIdx.x;
    const int bh  = blockIdx.x;       // b*128 + h
    const int bb  = bh >> 7, hh = bh & 127;
    const size_t rowb = (size_t)bb * Nc + (size_t)hh * Wc;

    // border zeros for this row: w in {0,1,126,127} x 256 ch (8B per thread)
    {
        const int wi = t >> 6;                       // 0..3
        const int w  = (wi & 2) ? (wi + 124) : wi;   // 0,1,126,127
        const int c8 = (t & 63) * 4;
        uint2 z; z.x = 0u; z.y = 0u;
        *(uint2*)(gsh + (rowb + w) * Cc + c8) = z;
    }
    __syncthreads();

    const int cg  = t & 31;           // channel group (8 ch): covers 256 ch
    const int wq  = t >> 5;           // w-quad 0..7
    const int c0  = cg * 8;
    const int s0  = c0 / CSZ - SPAD;
    const int s1  = (c0 + 4) / CSZ - SPAD;

#pragma unroll 1
    for (int qtr = 0; qtr < 4; ++qtr) {
        const int wbase = qtr * 32 + wq * 4 - 1;

        float acc[4][8];
        {
            float4 a0 = *(const float4*)(dw_b + c0);
            float4 a1 = *(const float4*)(dw_b + c0 + 4);
#pragma unroll
            for (int i = 0; i < 4; ++i) {
                acc[i][0] = a0.x; acc[i][1] = a0.y; acc[i][2] = a0.z; acc[i][3] = a0.w;
                acc[i][4] = a1.x; acc[i][5] = a1.y; acc[i][6] = a1.z; acc[i][7] = a1.w;
            }
        }

#pragma unroll
        for (int dy = -1; dy <= 1; ++dy) {
            const int y = hh + dy;
            if (y < 0 || y >= Hc) continue;          // block-uniform
            const unsigned short* rp = h1 + ((size_t)bb * Nc + (size_t)y * Wc) * Cc + c0;
            float in[6][8];
#pragma unroll
            for (int dx = 0; dx < 6; ++dx) {
                const int w = wbase + dx;
                ushort8 raw = {0, 0, 0, 0, 0, 0, 0, 0};
                if (w >= 0 && w < Wc) raw = *(const ushort8*)(rp + (size_t)w * Cc);
#pragma unroll
                for (int c = 0; c < 8; ++c) in[dx][c] = bf2f(raw[c]);
            }
            const float* wrow = dwT + (dy + 1) * 3 * Cc + c0;
            float wr[3][8];
#pragma unroll
            for (int tx = 0; tx < 3; ++tx) {
                float4 wa = *(const float4*)(wrow + tx * Cc);
                float4 wb = *(const float4*)(wrow + tx * Cc + 4);
                wr[tx][0] = wa.x; wr[tx][1] = wa.y; wr[tx][2] = wa.z; wr[tx][3] = wa.w;
                wr[tx][4] = wb.x; wr[tx][5] = wb.y; wr[tx][6] = wb.z; wr[tx][7] = wb.w;
            }
#pragma unroll
            for (int i = 0; i < 4; ++i)
#pragma unroll
                for (int tx = 0; tx < 3; ++tx)
#pragma unroll
                    for (int c = 0; c < 8; ++c)
                        acc[i][c] += in[i + tx][c] * wr[tx][c];
        }

#pragma unroll
        for (int i = 0; i < 4; ++i) {
            float g[8];
#pragma unroll
            for (int c = 0; c < 8; ++c) {
                const float v = acc[i][c];
                // gelu(v) ~= v * sigmoid(1.59576912*v + 0.07135482*v^3)
                const float u = v * v;
                const float a = __builtin_fmaf(0.0713548162f, u, 1.5957691216f);
                const float e = __expf(v * a);
                g[c] = v * e * __builtin_amdgcn_rcpf(e + 1.0f);
            }
            uint2 lo, hi;
            lo.x = pk2bf(g[0], g[1]); lo.y = pk2bf(g[2], g[3]);
            hi.x = pk2bf(g[4], g[5]); hi.y = pk2bf(g[6], g[7]);
            const int wo = wbase + 1 + i;
            const int w0 = wo + s0, w1 = wo + s1;
            if ((unsigned)w0 < (unsigned)Wc) *(uint2*)(gsh + (rowb + w0) * Cc + c0)     = lo;
            if ((unsigned)w1 < (unsigned)Wc) *(uint2*)(gsh + (rowb + w1) * Cc + c0 + 4) = hi;
        }
    }
}

// ---------------------------------------------------------------------------
// K3: out = g_shifted @ w2b^T + b2. Clone of fc1's structure: BOTH panels
// bf16 via async16, single-barrier 1-step-lookahead, zero staging VALU.
// Epilogue writes fp32 out directly. LDS 32768 -> 5 blocks/CU by LDS.
// (r5-proven.)
// ---------------------------------------------------------------------------
__global__ __launch_bounds__(256)
void fc2_mfma_kernel(const unsigned short* __restrict__ A, const unsigned short* __restrict__ w2b,
                     const float* __restrict__ b2, float* __restrict__ out)
{
    __shared__ __align__(16) unsigned char smem[32768];
    __bf16* As = (__bf16*)smem;                  // [2][128][32]
    __bf16* Bs = (__bf16*)(smem + 16384);        // [2][128][32]

    const int tid  = threadIdx.x;
    const int lane = tid & 63;
    const int wave = tid >> 6;
    const int wm = (wave >> 1) * 64, wn = (wave & 1) * 64;

    const int lid = ((blockIdx.x & 7) << 8) | (blockIdx.x >> 3);
    const size_t m0 = (size_t)(lid >> 1) * 128;
    const int j0 = (lid & 1) * 128;
    const int idx0 = tid, idx1 = tid + 256;

    const size_t aro0 = (m0 + (idx0 >> 2)) * Cc + (idx0 & 3) * 8;
    const size_t aro1 = (m0 + (idx1 >> 2)) * Cc + (idx1 & 3) * 8;
    const size_t bro0 = (size_t)(j0 + (idx0 >> 2)) * Cc + (idx0 & 3) * 8;
    const size_t bro1 = (size_t)(j0 + (idx1 >> 2)) * Cc + (idx1 & 3) * 8;

    auto stage = [&](int buf, int t) {
        const int k0 = t * 32;
        __bf16* adst = As + buf * 4096;
        __bf16* bdst = Bs + buf * 4096;
        async16(A   + aro0 + k0, adst + idx0 * 8);
        async16(A   + aro1 + k0, adst + idx1 * 8);
        async16(w2b + bro0 + k0, bdst + idx0 * 8);
        async16(w2b + bro1 + k0, bdst + idx1 * 8);
    };

    f32x4 acc[4][4] = {};
    const int kq = (lane >> 4) * 8;
    const int rr = lane & 15;

    stage(0, 0);
    __syncthreads();

    int cur = 0;
    for (int t = 0; t < 8; ++t) {
        const int nxt = cur ^ 1;
        if (t < 7) stage(nxt, t + 1);
        bf16x8 a[4], b[4];
        const __bf16* ap = As + cur * 4096;
        const __bf16* bp = Bs + cur * 4096;
#pragma unroll
        for (int i = 0; i < 4; ++i) {
            a[i] = *(const bf16x8*)(ap + (wm + i * 16 + rr) * 32 + kq);
            b[i] = *(const bf16x8*)(bp + (wn + i * 16 + rr) * 32 + kq);
        }
#pragma unroll
        for (int i = 0; i < 4; ++i)
#pragma unroll
            for (int j = 0; j < 4; ++j)
                acc[i][j] = __builtin_amdgcn_mfma_f32_16x16x32_bf16(a[i], b[j], acc[i][j], 0, 0, 0);
        __syncthreads();
        cur = nxt;
    }

    const int cq = (lane >> 4) * 4;
    const int cc = lane & 15;
    float bv[4];
#pragma unroll
    for (int j = 0; j < 4; ++j) bv[j] = b2[j0 + wn + j * 16 + cc];
#pragma unroll
    for (int i = 0; i < 4; ++i)
#pragma unroll
        for (int j = 0; j < 4; ++j) {
            const int col = j0 + wn + j * 16 + cc;
#pragma unroll
            for (int rg = 0; rg < 4; ++rg)
                out[(m0 + wm + i * 16 + cq + rg) * Cc + col] = acc[i][j][rg] + bv[j];
        }
}

extern "C" void kernel_launch(void* const* d_in, const int* in_sizes, int n_in,
                              void* d_out, int out_size, void* d_ws, size_t ws_size,
                              hipStream_t stream) {
    // inputs: x, H, W, w1, b1, dw_w, dw_b, w2, b2
    const float* x    = (const float*)d_in[0];
    const float* w1   = (const float*)d_in[3];
    const float* b1   = (const float*)d_in[4];
    const float* dw_w = (const float*)d_in[5];
    const float* dw_b = (const float*)d_in[6];
    const float* w2   = (const float*)d_in[7];
    const float* b2   = (const float*)d_in[8];
    float* out = (float*)d_out;

    // ws layout:
    //   [0,64MB)    h1 bf16
    //   [64,128MB)  gsh bf16 (double-serves as xb: fc1 consumes it before
    //               dwconv overwrites; stream-serial)
    //   [128MB..)   w1b bf16 (128 KB), w2b bf16 (128 KB), dwT fp32 (9 KB)
    unsigned short* h1  = (unsigned short*)d_ws;
    unsigned short* gsh = h1 + (size_t)Mtot * Cc;
    unsigned short* w1b = gsh + (size_t)Mtot * Cc;
    unsigned short* w2b = w1b + 65536;
    float*          dwT = (float*)(w2b + 65536);

    shiftwprep_kernel<<<dim3(4096), dim3(256), 0, stream>>>(x, gsh, w1, w2, dw_w, w1b, w2b, dwT);
    fc1_mfma_kernel<<<dim3(2 * Mtot / 128), dim3(256), 0, stream>>>(gsh, w1b, b1, h1);
    dwconv_gelu_scatter_kernel<<<dim3(Mtot / 128), dim3(256), 0, stream>>>(h1, dwT, dw_b, gsh);
    fc2_mfma_kernel<<<dim3(2 * Mtot / 128), dim3(256), 0, stream>>>(gsh, w2b, b2, out);
}

// Round 10
// 348.871 us; speedup vs baseline: 1.1240x; 1.0121x over previous
//
#include <hip/hip_runtime.h>
#include <hip/hip_bf16.h>
#include <math.h>

// B=8, H=W=128, C=hidden=256, N=16384, Mtot=131072.
#define Hc   128
#define Wc   128
#define Cc   256
#define Nc   (Hc * Wc)
#define Bn   8
#define Mtot (Bn * Nc)          // 131072
#define CSZ  52                 // ceil(256/5)
#define SPAD 2

typedef unsigned short ushort4v __attribute__((ext_vector_type(4)));
typedef unsigned short ushort8  __attribute__((ext_vector_type(8)));
typedef __bf16         bf16x8   __attribute__((ext_vector_type(8)));
typedef float          f32x4    __attribute__((ext_vector_type(4)));

__device__ __forceinline__ float bf2f(unsigned short u) {
    return __uint_as_float(((unsigned)u) << 16);
}
__device__ __forceinline__ unsigned short f2bf(float f) {   // RNE
    unsigned u = __float_as_uint(f);
    return (unsigned short)((u + 0x7fffu + ((u >> 16) & 1u)) >> 16);
}
// pack two floats -> two bf16 (a -> low16). Round-half-up (ok vs bf16 eps).
__device__ __forceinline__ unsigned pk2bf(float a, float b) {
    unsigned ua = __float_as_uint(a) + 0x8000u;
    unsigned ub = __float_as_uint(b) + 0x8000u;
    return __builtin_amdgcn_perm(ub, ua, 0x07060302);
}
__device__ __forceinline__ void async16(const void* g, void* l) {
    __builtin_amdgcn_global_load_lds(
        (const __attribute__((address_space(1))) unsigned*)g,
        (__attribute__((address_space(3))) unsigned*)l, 16, 0, 0);
}

// Counted-vmcnt fence + raw barrier (T4). lgkmcnt(0) is REQUIRED: without it
// a wave's pending ds_reads of buf T%3 can cross the barrier and race the
// next tile's global_load_lds DMA into a recycled buffer (r9 failed exactly
// this way: vmcnt-only fence -> absmax 0.038). vmcnt(N) counted so the
// 2-steps-ahead stage stays in flight across the barrier.
#define FENCE(vm) asm volatile("s_waitcnt vmcnt(" #vm ") lgkmcnt(0)\n\ts_barrier" ::: "memory")

// ---------------------------------------------------------------------------
// P0+P1 merged: H-shift + fp32->bf16 convert of x (all 4096 blocks), plus
// weight prep (blocks 0..63): w1,w2 fp32->bf16; dw_w [ch][tap]->dwT [tap][ch].
// ---------------------------------------------------------------------------
__global__ __launch_bounds__(256)
void shiftwprep_kernel(const float* __restrict__ x, unsigned short* __restrict__ xb,
                       const float* __restrict__ w1, const float* __restrict__ w2,
                       const float* __restrict__ dw_w,
                       unsigned short* __restrict__ w1b, unsigned short* __restrict__ w2b,
                       float* __restrict__ dwT)
{
    const int gid0 = blockIdx.x * 256 + threadIdx.x;
    if (blockIdx.x < 64) {                            // weight prep (16384 thr)
        const int g = gid0;
        {
            float4 a = *(const float4*)(w1 + (size_t)g * 4);
            ushort4v o = { f2bf(a.x), f2bf(a.y), f2bf(a.z), f2bf(a.w) };
            *(ushort4v*)(w1b + (size_t)g * 4) = o;
        }
        {
            float4 a = *(const float4*)(w2 + (size_t)g * 4);
            ushort4v o = { f2bf(a.x), f2bf(a.y), f2bf(a.z), f2bf(a.w) };
            *(ushort4v*)(w2b + (size_t)g * 4) = o;
        }
        if (g < 9 * Cc) dwT[(g % 9) * Cc + g / 9] = dw_w[g];
    }
#pragma unroll
    for (int it = 0; it < 4; ++it) {
        const int gid = gid0 + it * (4096 * 256);   // 4.19M chunks total
        const int row = gid >> 5;                   // b*16384 + h*128 + w
        const int c   = (gid & 31) * 8;
        const int hh  = (row >> 7) & 127;
        const int s0  = c / CSZ - SPAD;
        const int s1  = (c + 4) / CSZ - SPAD;
        const int h0  = hh - s0, h1r = hh - s1;
        float4 v0 = make_float4(0.f, 0.f, 0.f, 0.f);
        float4 v1 = make_float4(0.f, 0.f, 0.f, 0.f);
        if (h0  >= 0 && h0  < Hc)
            v0 = *(const float4*)(x + ((size_t)row + (size_t)(h0 - hh) * Wc) * Cc + c);
        if (h1r >= 0 && h1r < Hc)
            v1 = *(const float4*)(x + ((size_t)row + (size_t)(h1r - hh) * Wc) * Cc + c + 4);
        uint4 o;
        o.x = pk2bf(v0.x, v0.y); o.y = pk2bf(v0.z, v0.w);
        o.z = pk2bf(v1.x, v1.y); o.w = pk2bf(v1.z, v1.w);
        *(uint4*)(xb + (size_t)row * Cc + c) = o;
    }
}

// ---------------------------------------------------------------------------
// K1: h1 = x_shifted_bf16 @ w1^T + b1. Both panels async16, 3-BUFFER
// 2-step-lookahead with counted vmcnt fences (stage(t+2) in flight across
// every barrier; vmcnt(4) steady, vmcnt(0) only at T=6). LDS 49152
// (3 x (A 8KB + B 8KB); Cs epilogue unions) -> 3 blocks/CU.
// ---------------------------------------------------------------------------
__global__ __launch_bounds__(256)
void fc1_mfma_kernel(const unsigned short* __restrict__ xb, const unsigned short* __restrict__ w1b,
                     const float* __restrict__ b1, unsigned short* __restrict__ h1)
{
    __shared__ __align__(16) unsigned char smem[49152];
    __bf16* base = (__bf16*)smem;                   // buf k: A at k*8192, B at +4096 (elems)
    unsigned short* Cs = (unsigned short*)smem;     // [128][136] epilogue union

    const int tid  = threadIdx.x;
    const int lane = tid & 63;
    const int wave = tid >> 6;
    const int wm = (wave >> 1) * 64, wn = (wave & 1) * 64;

    // nwg = 2048 (div by 8): bijective XCD swizzle.
    const int lid = ((blockIdx.x & 7) << 8) | (blockIdx.x >> 3);
    const int bx  = lid >> 1;                  // b*128 + h
    const int j0  = (lid & 1) * 128;
    const size_t m0 = (size_t)bx * 128;
    const int idx0 = tid, idx1 = tid + 256;    // 16B chunks per panel

    const size_t aro0 = (m0 + (idx0 >> 2)) * Cc + (idx0 & 3) * 8;
    const size_t aro1 = (m0 + (idx1 >> 2)) * Cc + (idx1 & 3) * 8;
    const size_t bro0 = (size_t)(j0 + (idx0 >> 2)) * Cc + (idx0 & 3) * 8;
    const size_t bro1 = (size_t)(j0 + (idx1 >> 2)) * Cc + (idx1 & 3) * 8;

    auto stage = [&](int buf, int t) {         // 4 async16/thread = 4 vmcnt
        const int k0 = t * 32;
        __bf16* adst = base + buf * 8192;
        __bf16* bdst = adst + 4096;
        async16(xb  + aro0 + k0, adst + idx0 * 8);
        async16(xb  + aro1 + k0, adst + idx1 * 8);
        async16(w1b + bro0 + k0, bdst + idx0 * 8);
        async16(w1b + bro1 + k0, bdst + idx1 * 8);
    };

    f32x4 acc[4][4] = {};
    const int kq = (lane >> 4) * 8;
    const int rr = lane & 15;

    // prologue: 2 tiles in flight; wait tile0, keep tile1 flying.
    stage(0, 0);
    stage(1, 1);
    FENCE(4);

#define G1_STEP(T, FN)                                                        \
    {                                                                          \
        if constexpr ((T) <= 5) stage(((T) + 2) % 3, (T) + 2);                 \
        bf16x8 a[4], b[4];                                                     \
        const __bf16* ap = base + ((T) % 3) * 8192;                            \
        const __bf16* bp = ap + 4096;                                          \
        _Pragma("unroll")                                                      \
        for (int i = 0; i < 4; ++i) {                                          \
            a[i] = *(const bf16x8*)(ap + (wm + i * 16 + rr) * 32 + kq);        \
            b[i] = *(const bf16x8*)(bp + (wn + i * 16 + rr) * 32 + kq);        \
        }                                                                      \
        _Pragma("unroll")                                                      \
        for (int i = 0; i < 4; ++i)                                            \
            _Pragma("unroll")                                                  \
            for (int j = 0; j < 4; ++j)                                        \
                acc[i][j] = __builtin_amdgcn_mfma_f32_16x16x32_bf16(a[i], b[j], acc[i][j], 0, 0, 0); \
        FN;                                                                    \
    }

    G1_STEP(0, FENCE(4));
    G1_STEP(1, FENCE(4));
    G1_STEP(2, FENCE(4));
    G1_STEP(3, FENCE(4));
    G1_STEP(4, FENCE(4));
    G1_STEP(5, FENCE(4));
    G1_STEP(6, FENCE(0));
    G1_STEP(7, __syncthreads());   // all waves done reading bufs before Cs
#undef G1_STEP

    const int cq = (lane >> 4) * 4;
    const int cc = lane & 15;
    float bv[4];
#pragma unroll
    for (int j = 0; j < 4; ++j) bv[j] = b1[j0 + wn + j * 16 + cc];
#pragma unroll
    for (int i = 0; i < 4; ++i)
#pragma unroll
        for (int j = 0; j < 4; ++j) {
            const int col = wn + j * 16 + cc;
#pragma unroll
            for (int rg = 0; rg < 4; ++rg)
                Cs[(wm + i * 16 + cq + rg) * 136 + col] = f2bf(acc[i][j][rg] + bv[j]);
        }
    __syncthreads();
    {
        const int row = tid >> 1, hf = tid & 1;
        const unsigned short* src = Cs + row * 136 + hf * 64;
        unsigned short* dst = h1 + (m0 + row) * Cc + j0 + hf * 64;
#pragma unroll
        for (int i = 0; i < 8; ++i)
            *(uint4*)(dst + i * 8) = *(const uint4*)(src + i * 8);
    }
}

// ---------------------------------------------------------------------------
// K2: depthwise 3x3 + bias + GELU + W-shift scatter, ONE BLOCK PER (b,h) ROW
// (grid 1024). Owns all writes to its gsh row: border zeros + barrier + the
// r5-proven quarter-row scatter loop. (r8-proven, unchanged.)
// ---------------------------------------------------------------------------
__global__ __launch_bounds__(256)
void dwconv_gelu_scatter_kernel(const unsigned short* __restrict__ h1,
                                const float* __restrict__ dwT, const float* __restrict__ dw_b,
                                unsigned short* __restrict__ gsh)
{
    const int t   = threadIdx.x;
    const int bh  = blockIdx.x;       // b*128 + h
    const int bb  = bh >> 7, hh = bh & 127;
    const size_t rowb = (size_t)bb * Nc + (size_t)hh * Wc;

    // border zeros for this row: w in {0,1,126,127} x 256 ch (8B per thread)
    {
        const int wi = t >> 6;                       // 0..3
        const int w  = (wi & 2) ? (wi + 124) : wi;   // 0,1,126,127
        const int c8 = (t & 63) * 4;
        uint2 z; z.x = 0u; z.y = 0u;
        *(uint2*)(gsh + (rowb + w) * Cc + c8) = z;
    }
    __syncthreads();

    const int cg  = t & 31;           // channel group (8 ch): covers 256 ch
    const int wq  = t >> 5;           // w-quad 0..7
    const int c0  = cg * 8;
    const int s0  = c0 / CSZ - SPAD;
    const int s1  = (c0 + 4) / CSZ - SPAD;

#pragma unroll 1
    for (int qtr = 0; qtr < 4; ++qtr) {
        const int wbase = qtr * 32 + wq * 4 - 1;

        float acc[4][8];
        {
            float4 a0 = *(const float4*)(dw_b + c0);
            float4 a1 = *(const float4*)(dw_b + c0 + 4);
#pragma unroll
            for (int i = 0; i < 4; ++i) {
                acc[i][0] = a0.x; acc[i][1] = a0.y; acc[i][2] = a0.z; acc[i][3] = a0.w;
                acc[i][4] = a1.x; acc[i][5] = a1.y; acc[i][6] = a1.z; acc[i][7] = a1.w;
            }
        }

#pragma unroll
        for (int dy = -1; dy <= 1; ++dy) {
            const int y = hh + dy;
            if (y < 0 || y >= Hc) continue;          // block-uniform
            const unsigned short* rp = h1 + ((size_t)bb * Nc + (size_t)y * Wc) * Cc + c0;
            float in[6][8];
#pragma unroll
            for (int dx = 0; dx < 6; ++dx) {
                const int w = wbase + dx;
                ushort8 raw = {0, 0, 0, 0, 0, 0, 0, 0};
                if (w >= 0 && w < Wc) raw = *(const ushort8*)(rp + (size_t)w * Cc);
#pragma unroll
                for (int c = 0; c < 8; ++c) in[dx][c] = bf2f(raw[c]);
            }
            const float* wrow = dwT + (dy + 1) * 3 * Cc + c0;
            float wr[3][8];
#pragma unroll
            for (int tx = 0; tx < 3; ++tx) {
                float4 wa = *(const float4*)(wrow + tx * Cc);
                float4 wb = *(const float4*)(wrow + tx * Cc + 4);
                wr[tx][0] = wa.x; wr[tx][1] = wa.y; wr[tx][2] = wa.z; wr[tx][3] = wa.w;
                wr[tx][4] = wb.x; wr[tx][5] = wb.y; wr[tx][6] = wb.z; wr[tx][7] = wb.w;
            }
#pragma unroll
            for (int i = 0; i < 4; ++i)
#pragma unroll
                for (int tx = 0; tx < 3; ++tx)
#pragma unroll
                    for (int c = 0; c < 8; ++c)
                        acc[i][c] += in[i + tx][c] * wr[tx][c];
        }

#pragma unroll
        for (int i = 0; i < 4; ++i) {
            float g[8];
#pragma unroll
            for (int c = 0; c < 8; ++c) {
                const float v = acc[i][c];
                // gelu(v) ~= v * sigmoid(1.59576912*v + 0.07135482*v^3)
                const float u = v * v;
                const float a = __builtin_fmaf(0.0713548162f, u, 1.5957691216f);
                const float e = __expf(v * a);
                g[c] = v * e * __builtin_amdgcn_rcpf(e + 1.0f);
            }
            uint2 lo, hi;
            lo.x = pk2bf(g[0], g[1]); lo.y = pk2bf(g[2], g[3]);
            hi.x = pk2bf(g[4], g[5]); hi.y = pk2bf(g[6], g[7]);
            const int wo = wbase + 1 + i;
            const int w0 = wo + s0, w1 = wo + s1;
            if ((unsigned)w0 < (unsigned)Wc) *(uint2*)(gsh + (rowb + w0) * Cc + c0)     = lo;
            if ((unsigned)w1 < (unsigned)Wc) *(uint2*)(gsh + (rowb + w1) * Cc + c0 + 4) = hi;
        }
    }
}

// ---------------------------------------------------------------------------
// K3: out = g_shifted @ w2b^T + b2. Same 3-buffer counted-vmcnt pipeline as
// fc1; epilogue writes fp32 out directly (no Cs). LDS 49152 -> 3 blocks/CU.
// ---------------------------------------------------------------------------
__global__ __launch_bounds__(256)
void fc2_mfma_kernel(const unsigned short* __restrict__ A, const unsigned short* __restrict__ w2b,
                     const float* __restrict__ b2, float* __restrict__ out)
{
    __shared__ __align__(16) unsigned char smem[49152];
    __bf16* base = (__bf16*)smem;                // buf k: A at k*8192, B at +4096

    const int tid  = threadIdx.x;
    const int lane = tid & 63;
    const int wave = tid >> 6;
    const int wm = (wave >> 1) * 64, wn = (wave & 1) * 64;

    const int lid = ((blockIdx.x & 7) << 8) | (blockIdx.x >> 3);
    const size_t m0 = (size_t)(lid >> 1) * 128;
    const int j0 = (lid & 1) * 128;
    const int idx0 = tid, idx1 = tid + 256;

    const size_t aro0 = (m0 + (idx0 >> 2)) * Cc + (idx0 & 3) * 8;
    const size_t aro1 = (m0 + (idx1 >> 2)) * Cc + (idx1 & 3) * 8;
    const size_t bro0 = (size_t)(j0 + (idx0 >> 2)) * Cc + (idx0 & 3) * 8;
    const size_t bro1 = (size_t)(j0 + (idx1 >> 2)) * Cc + (idx1 & 3) * 8;

    auto stage = [&](int buf, int t) {
        const int k0 = t * 32;
        __bf16* adst = base + buf * 8192;
        __bf16* bdst = adst + 4096;
        async16(A   + aro0 + k0, adst + idx0 * 8);
        async16(A   + aro1 + k0, adst + idx1 * 8);
        async16(w2b + bro0 + k0, bdst + idx0 * 8);
        async16(w2b + bro1 + k0, bdst + idx1 * 8);
    };

    f32x4 acc[4][4] = {};
    const int kq = (lane >> 4) * 8;
    const int rr = lane & 15;

    stage(0, 0);
    stage(1, 1);
    FENCE(4);

#define G2_STEP(T, FN)                                                        \
    {                                                                          \
        if constexpr ((T) <= 5) stage(((T) + 2) % 3, (T) + 2);                 \
        bf16x8 a[4], b[4];                                                     \
        const __bf16* ap = base + ((T) % 3) * 8192;                            \
        const __bf16* bp = ap + 4096;                                          \
        _Pragma("unroll")                                                      \
        for (int i = 0; i < 4; ++i) {                                          \
            a[i] = *(const bf16x8*)(ap + (wm + i * 16 + rr) * 32 + kq);        \
            b[i] = *(const bf16x8*)(bp + (wn + i * 16 + rr) * 32 + kq);        \
        }                                                                      \
        _Pragma("unroll")                                                      \
        for (int i = 0; i < 4; ++i)                                            \
            _Pragma("unroll")                                                  \
            for (int j = 0; j < 4; ++j)                                        \
                acc[i][j] = __builtin_amdgcn_mfma_f32_16x16x32_bf16(a[i], b[j], acc[i][j], 0, 0, 0); \
        FN;                                                                    \
    }

    G2_STEP(0, FENCE(4));
    G2_STEP(1, FENCE(4));
    G2_STEP(2, FENCE(4));
    G2_STEP(3, FENCE(4));
    G2_STEP(4, FENCE(4));
    G2_STEP(5, FENCE(4));
    G2_STEP(6, FENCE(0));
    G2_STEP(7, ;);
#undef G2_STEP

    const int cq = (lane >> 4) * 4;
    const int cc = lane & 15;
    float bv[4];
#pragma unroll
    for (int j = 0; j < 4; ++j) bv[j] = b2[j0 + wn + j * 16 + cc];
#pragma unroll
    for (int i = 0; i < 4; ++i)
#pragma unroll
        for (int j = 0; j < 4; ++j) {
            const int col = j0 + wn + j * 16 + cc;
#pragma unroll
            for (int rg = 0; rg < 4; ++rg)
                out[(m0 + wm + i * 16 + cq + rg) * Cc + col] = acc[i][j][rg] + bv[j];
        }
}

extern "C" void kernel_launch(void* const* d_in, const int* in_sizes, int n_in,
                              void* d_out, int out_size, void* d_ws, size_t ws_size,
                              hipStream_t stream) {
    // inputs: x, H, W, w1, b1, dw_w, dw_b, w2, b2
    const float* x    = (const float*)d_in[0];
    const float* w1   = (const float*)d_in[3];
    const float* b1   = (const float*)d_in[4];
    const float* dw_w = (const float*)d_in[5];
    const float* dw_b = (const float*)d_in[6];
    const float* w2   = (const float*)d_in[7];
    const float* b2   = (const float*)d_in[8];
    float* out = (float*)d_out;

    // ws layout:
    //   [0,64MB)    h1 bf16
    //   [64,128MB)  gsh bf16 (double-serves as xb: fc1 consumes it before
    //               dwconv overwrites; stream-serial)
    //   [128MB..)   w1b bf16 (128 KB), w2b bf16 (128 KB), dwT fp32 (9 KB)
    unsigned short* h1  = (unsigned short*)d_ws;
    unsigned short* gsh = h1 + (size_t)Mtot * Cc;
    unsigned short* w1b = gsh + (size_t)Mtot * Cc;
    unsigned short* w2b = w1b + 65536;
    float*          dwT = (float*)(w2b + 65536);

    shiftwprep_kernel<<<dim3(4096), dim3(256), 0, stream>>>(x, gsh, w1, w2, dw_w, w1b, w2b, dwT);
    fc1_mfma_kernel<<<dim3(2 * Mtot / 128), dim3(256), 0, stream>>>(gsh, w1b, b1, h1);
    dwconv_gelu_scatter_kernel<<<dim3(Mtot / 128), dim3(256), 0, stream>>>(h1, dwT, dw_b, gsh);
    fc2_mfma_kernel<<<dim3(2 * Mtot / 128), dim3(256), 0, stream>>>(gsh, w2b, b2, out);
}